// Round 7
// baseline (348.813 us; speedup 1.0000x reference)
//
#include <hip/hip_runtime.h>
#include <stdint.h>

#define TT 512
#define XSTR 516 // x row stride (floats)

typedef float    f32x4 __attribute__((ext_vector_type(4)));
typedef short    s16x8 __attribute__((ext_vector_type(8)));
typedef __fp16   h16x2 __attribute__((ext_vector_type(2)));
typedef _Float16 f16x8 __attribute__((ext_vector_type(8)));

#define MFMA_F16(A, B, C) \
    __builtin_amdgcn_mfma_f32_16x16x32_f16( \
        __builtin_bit_cast(f16x8, (A)), (B), (C), 0, 0, 0)

#define LOG2E  1.442695040888963f
#define LOG2E2 2.885390081777927f

// R14: barrier-free in-wave GRU. Evidence R9-R13: every barrier-coupled
// structure pays ~720-1130 cyc per 16 batch-steps/CU regardless of TLP/
// ILP shape -- the barrier serializes one chain per wg. Fix: each WAVE
// is an independent 4-batch scan over the full H=64. A rows = batches
// replicated x4 (row r = batch r&3); n packs gate||hidden (12 tiles);
// k=64 (2 chunks) -> 24 MFMA/step. D: every lane's regs 0-3 = batches
// 0-3 of col n16 (4q+r & 3 = r); quad p keeps col-tile p via 36 cndmask.
// h exchange = wave-private 512B LDS, rotated 16B groups (2-way banks,
// free): write 4x ds_write_b16, read 2x ds_read_b128 -- same-wave DS
// ordering, NO barrier in the whole t-loop. 1024 waves = 1 per SIMD on
// the whole chip; launch_bounds(256,1) -> 512-VGPR budget.
__global__ __launch_bounds__(256, 1) void gru_scan_kernel(
    const float* __restrict__ x,     // (4096, 512, 1)
    const float* __restrict__ Wih,   // (192, 1)
    const float* __restrict__ Whh,   // (192, 64)
    const float* __restrict__ bih,   // (192)
    const float* __restrict__ bhh,   // (192)
    const float* __restrict__ Wout,  // (1, 64)
    const float* __restrict__ bout,  // (1)
    float* __restrict__ out)         // (4096, 1)
{
    __shared__ __align__(16) float xs[16 * XSTR];   // 33 KB
    __shared__ __align__(16) short hx[4][2][256];   // wave-private, 4 KB

    const int tid  = threadIdx.x;
    const int w    = tid >> 6;
    const int L    = tid & 63;
    const int n16  = L & 15;
    const int quad = L >> 4;
    const int q    = quad * 16 + n16;   // col this lane does MATH for
    const int bb0  = blockIdx.x * 16;

    // ---- stage x batch-major: xs[b][t] (proven R12 staging) ----
    #pragma unroll
    for (int k = 0; k < 8; ++k) {
        int idx = tid + k * 256;          // 0..2047
        int row = idx >> 7;               // batch row 0..15
        int t4  = idx & 127;              // t/4
        f32x4 v = *(const f32x4*)(x + (size_t)(bb0 + row) * TT + t4 * 4);
        *(f32x4*)(xs + row * XSTR + t4 * 4) = v;
    }
    // ---- zero own wave's exchange (1 KB: 64 lanes x 16B) ----
    {
        f32x4 zv = {0.f, 0.f, 0.f, 0.f};
        *(f32x4*)((short*)hx[w] + L * 8) = zv;
    }

    // ---- per-lane constants (gate scales folded), col q ----
    const float wr2   = -LOG2E  * Wih[q];
    const float wz2   = -LOG2E  * Wih[64 + q];
    const float wn2   =  LOG2E2 * Wih[128 + q];
    const float bR2   = -LOG2E  * (bih[q]      + bhh[q]);
    const float bZ2   = -LOG2E  * (bih[64 + q] + bhh[64 + q]);
    const float bN2   =  LOG2E2 * bhh[128 + q];
    const float bihn2 =  LOG2E2 * bih[128 + q];
    const float wo    = Wout[q];

    const f32x4 zero4 = {0.f, 0.f, 0.f, 0.f};

    // ---- W_hh B-fragments: tile (g, colgroup cg), k-chunk c ----
    // B[k = c*32 + quad*8 + j][n = cg*16 + n16], scaled
    f16x8 Bf[3][4][2];
    #pragma unroll
    for (int g = 0; g < 3; ++g) {
        const float sg = (g == 2) ? LOG2E2 : -LOG2E;
        #pragma unroll
        for (int cg = 0; cg < 4; ++cg) {
            #pragma unroll
            for (int c = 0; c < 2; ++c) {
                const float* p = Whh + ((g * 64 + cg * 16 + n16) * 64 + c * 32 + quad * 8);
                #pragma unroll
                for (int j = 0; j < 8; ++j)
                    Bf[g][cg][c][j] = (_Float16)(p[j] * sg);
            }
        }
    }

    __syncthreads();   // xs visible (only barrier in the kernel body)

    // ---- exchange addressing: layout [b][group][8 f16], group rotated
    // by 2b so reads AND writes are uniform 2-way (free, m136) ----
    const int brd = n16 & 3;   // batch this lane reads (A row = n16)
    const int rs0 = brd * 8 + ((quad + 2 * brd) & 7);       // k 0..31
    const int rs1 = brd * 8 + ((quad + 4 + 2 * brd) & 7);   // k 32..63
    int wA[4];
    {
        const int g0 = q >> 3;
        #pragma unroll
        for (int b = 0; b < 4; ++b)
            wA[b] = b * 64 + (((g0 + 2 * b) & 7) << 3) + (q & 7);
    }

    const s16x8* hv = (const s16x8*)hx[w];   // 64 slots (2 bufs x 32)
    const bool sq1  = (quad & 1) != 0;
    const bool sq23 = quad >= 2;

    // persistent h (fp32): batches 0..3 of col q (wave's batch group)
    f32x4 hD  = {0.f, 0.f, 0.f, 0.f};
    f32x4 hm1 = {-1.f, -1.f, -1.f, -1.f};   // h - 1, carried off-chain

    auto step = [&](int cur, f32x4 xv) {
        s16x8 A0 = hv[cur * 32 + rs0];
        s16x8 A1 = hv[cur * 32 + rs1];

        // x terms: independent of A -> scheduled into the read/MFMA shadow
        f32x4 xrv = xv * wr2 + bR2;
        f32x4 xzv = xv * wz2 + bZ2;
        f32x4 xnv = xv * wn2 + bihn2;

        f32x4 aRt[4], aNt[4], aZt[4];
        #pragma unroll
        for (int cg = 0; cg < 4; ++cg) aRt[cg] = MFMA_F16(A0, Bf[0][cg][0], zero4);
        #pragma unroll
        for (int cg = 0; cg < 4; ++cg) aRt[cg] = MFMA_F16(A1, Bf[0][cg][1], aRt[cg]);
        #pragma unroll
        for (int cg = 0; cg < 4; ++cg) aNt[cg] = MFMA_F16(A0, Bf[2][cg][0], zero4);
        #pragma unroll
        for (int cg = 0; cg < 4; ++cg) aNt[cg] = MFMA_F16(A1, Bf[2][cg][1], aNt[cg]);
        #pragma unroll
        for (int cg = 0; cg < 4; ++cg) aZt[cg] = MFMA_F16(A0, Bf[1][cg][0], zero4);
        #pragma unroll
        for (int cg = 0; cg < 4; ++cg) aZt[cg] = MFMA_F16(A1, Bf[1][cg][1], aZt[cg]);

        // quad p consumes col-tile p (36 cndmask total)
        f32x4 aR = sq23 ? (sq1 ? aRt[3] : aRt[2]) : (sq1 ? aRt[1] : aRt[0]);
        f32x4 aN = sq23 ? (sq1 ? aNt[3] : aNt[2]) : (sq1 ? aNt[1] : aNt[0]);
        f32x4 aZ = sq23 ? (sq1 ? aZt[3] : aZt[2]) : (sq1 ? aZt[1] : aZt[0]);

        f32x4 ar = xrv + aR;
        f32x4 Er = {__builtin_amdgcn_exp2f(ar[0]), __builtin_amdgcn_exp2f(ar[1]),
                    __builtin_amdgcn_exp2f(ar[2]), __builtin_amdgcn_exp2f(ar[3])};
        f32x4 DR = Er + 1.0f;
        f32x4 r  = {__builtin_amdgcn_rcpf(DR[0]), __builtin_amdgcn_rcpf(DR[1]),
                    __builtin_amdgcn_rcpf(DR[2]), __builtin_amdgcn_rcpf(DR[3])};
        f32x4 aNb = aN + bN2;                // off critical path (|| exp2/rcp)
        f32x4 an  = r * aNb + xnv;
        f32x4 En = {__builtin_amdgcn_exp2f(an[0]), __builtin_amdgcn_exp2f(an[1]),
                    __builtin_amdgcn_exp2f(an[2]), __builtin_amdgcn_exp2f(an[3])};
        f32x4 DN = En + 1.0f;
        f32x4 az = xzv + aZ;
        f32x4 Ez = {__builtin_amdgcn_exp2f(az[0]), __builtin_amdgcn_exp2f(az[1]),
                    __builtin_amdgcn_exp2f(az[2]), __builtin_amdgcn_exp2f(az[3])};
        f32x4 DZ = Ez + 1.0f;
        f32x4 P  = DZ * DN;
        f32x4 iq = {__builtin_amdgcn_rcpf(P[0]), __builtin_amdgcn_rcpf(P[1]),
                    __builtin_amdgcn_rcpf(P[2]), __builtin_amdgcn_rcpf(P[3])};
        f32x4 z  = iq * DN;                  // = 1/DZ = sigmoid(pre_z)
        f32x4 rn = iq * DZ;                  // = 1/DN
        f32x4 n  = rn * -2.0f + 1.0f;        // tanh
        f32x4 s  = rn *  2.0f + hm1;         // h_prev - n
        f32x4 hn = z * s + n;                // (1-z)n + z h

        hD  = hn;
        hm1 = hn - 1.0f;

        h16x2 pk01 = __builtin_amdgcn_cvt_pkrtz(hn[0], hn[1]);
        h16x2 pk23 = __builtin_amdgcn_cvt_pkrtz(hn[2], hn[3]);
        unsigned u01 = __builtin_bit_cast(unsigned, pk01);
        unsigned u23 = __builtin_bit_cast(unsigned, pk23);
        short* wh = (short*)hx[w] + (cur ^ 1) * 256;
        wh[wA[0]] = (short)(u01 & 0xffffu);
        wh[wA[1]] = (short)(u01 >> 16);
        wh[wA[2]] = (short)(u23 & 0xffffu);
        wh[wA[3]] = (short)(u23 >> 16);
    };

    const float* xp0 = xs + (w * 4 + 0) * XSTR;
    const float* xp1 = xs + (w * 4 + 1) * XSTR;
    const float* xp2 = xs + (w * 4 + 2) * XSTR;
    const float* xp3 = xs + (w * 4 + 3) * XSTR;

    for (int t = 0; t < TT; t += 4) {
        f32x4 xa0 = *(const f32x4*)(xp0 + t);   // broadcast reads
        f32x4 xa1 = *(const f32x4*)(xp1 + t);
        f32x4 xa2 = *(const f32x4*)(xp2 + t);
        f32x4 xa3 = *(const f32x4*)(xp3 + t);
        step(0, f32x4{xa0[0], xa1[0], xa2[0], xa3[0]});
        step(1, f32x4{xa0[1], xa1[1], xa2[1], xa3[1]});
        step(0, f32x4{xa0[2], xa1[2], xa2[2], xa3[2]});
        step(1, f32x4{xa0[3], xa1[3], xa2[3], xa3[3]});
    }

    // ---- epilogue: wave-local; out[b] = sum_q h[b][q]*Wout[q] + bout ----
    float p0 = hD[0] * wo;
    float p1 = hD[1] * wo;
    float p2 = hD[2] * wo;
    float p3 = hD[3] * wo;
    #pragma unroll
    for (int mask = 1; mask <= 32; mask <<= 1) {
        p0 += __shfl_xor(p0, mask, 64);
        p1 += __shfl_xor(p1, mask, 64);
        p2 += __shfl_xor(p2, mask, 64);
        p3 += __shfl_xor(p3, mask, 64);
    }
    if (L == 0) {
        const float bo = bout[0];
        out[bb0 + w * 4 + 0] = p0 + bo;
        out[bb0 + w * 4 + 1] = p1 + bo;
        out[bb0 + w * 4 + 2] = p2 + bo;
        out[bb0 + w * 4 + 3] = p3 + bo;
    }
}

extern "C" void kernel_launch(void* const* d_in, const int* in_sizes, int n_in,
                              void* d_out, int out_size, void* d_ws, size_t ws_size,
                              hipStream_t stream) {
    (void)in_sizes; (void)n_in; (void)d_ws; (void)ws_size; (void)out_size;
    const float* x    = (const float*)d_in[0];
    const float* Wih  = (const float*)d_in[1];
    const float* Whh  = (const float*)d_in[2];
    const float* bih  = (const float*)d_in[3];
    const float* bhh  = (const float*)d_in[4];
    const float* Wout = (const float*)d_in[5];
    const float* bout = (const float*)d_in[6];
    float* out = (float*)d_out;

    gru_scan_kernel<<<dim3(4096 / 16), dim3(256), 0, stream>>>(
        x, Wih, Whh, bih, bhh, Wout, bout, out);
}

// Round 9
// 221.126 us; speedup vs baseline: 1.5774x; 1.5774x over previous
//
#include <hip/hip_runtime.h>
#include <stdint.h>

#define TT 512
#define BT 8    // 4096/8 = 512 wgs -> 2 wgs/CU -> 2 waves/SIMD (no dup work)
#define XSTR 516  // x row stride (floats): spreads t-columns across banks

typedef float    f32x4 __attribute__((ext_vector_type(4)));
typedef float    f32x2 __attribute__((ext_vector_type(2)));
typedef short    s16x8 __attribute__((ext_vector_type(8)));
typedef __fp16   h16x2 __attribute__((ext_vector_type(2)));
typedef _Float16 f16x8 __attribute__((ext_vector_type(8)));

#define MFMA_F16(A, B, C) \
    __builtin_amdgcn_mfma_f32_16x16x32_f16( \
        __builtin_bit_cast(f16x8, (A)), (B), (C), 0, 0, 0)

#define LOG2E  1.442695040888963f
#define LOG2E2 2.885390081777927f

// R15 (resubmit; prior bench died to container infra, no signal) =
// R9 (153us champion, structure proven optimal over R10-R14 lattice)
// + chain surgery only:
//  - split-C MFMA for R,N gates (parallel pair + add: -1 MFMA dep at head)
//  - x-terms precomputed at group load (off the recurrence chain)
//  - hm1 carry: s = 2*rn + hm1 (removes hp-n dep; h rebuilt in epilogue)
//  - x group prefetched one iteration ahead (no LDS x-read on chain)
//  - setprio(1) over chain head / 0 over tail: with 2 co-resident wgs this
//    is T5's role-diversity case and should stabilize anti-phase.
// Everything else (layout, swizzle, dbuf, 4-step unroll, sleep stagger,
// epilogue) is R9 verbatim.
__global__ __launch_bounds__(256, 2) void gru_scan_kernel(
    const float* __restrict__ x,     // (4096, 512, 1)
    const float* __restrict__ Wih,   // (192, 1)
    const float* __restrict__ Whh,   // (192, 64)
    const float* __restrict__ bih,   // (192)
    const float* __restrict__ bhh,   // (192)
    const float* __restrict__ Wout,  // (1, 64)
    const float* __restrict__ bout,  // (1)
    float* __restrict__ out)         // (4096, 1)
{
    __shared__ __align__(16) float xs[BT * XSTR];  // x batch-major [b][t], 16.5 KB
    __shared__ __align__(16) short hbuf[2][1024];  // [dbuf][slot*8+j], 4 KB
    __shared__ float outp[4][BT];

    const int tid  = threadIdx.x;
    const int w    = tid >> 6;
    const int L    = tid & 63;
    const int n16  = L & 15;
    const int quad = L >> 4;
    const int q    = w * 16 + n16;   // hidden col owned by this lane
    const int b0   = blockIdx.x * BT;

    // ---- stage x batch-major: xs[b][t] ----
    #pragma unroll
    for (int k = 0; k < 4; ++k) {
        int idx = tid + k * 256;          // 0..1023
        int row = idx >> 7;               // batch row 0..7
        int t4  = idx & 127;              // t/4
        f32x4 v = *(const f32x4*)(x + (size_t)(b0 + row) * TT + t4 * 4);
        *(f32x4*)(xs + row * XSTR + t4 * 4) = v;   // 16B-aligned (516*4%16==0)
    }
    // ---- zero both h double-buffers (4 KB = 256 f32x4) ----
    {
        f32x4* hb = (f32x4*)hbuf;
        f32x4 zv = {0.f, 0.f, 0.f, 0.f};
        hb[tid] = zv;
    }

    // ---- per-lane constants (gate scales folded) ----
    const float wr2   = -LOG2E  * Wih[q];
    const float wz2   = -LOG2E  * Wih[64 + q];
    const float wn2   =  LOG2E2 * Wih[128 + q];
    const float bR2   = -LOG2E  * (bih[q]      + bhh[q]);
    const float bZ2   = -LOG2E  * (bih[64 + q] + bhh[64 + q]);
    const float bN2   =  LOG2E2 * bhh[128 + q];
    const float bihn2 =  LOG2E2 * bih[128 + q];
    const float wo    = Wout[q];

    const f32x4 bR4   = {bR2, bR2, bR2, bR2};
    const f32x4 bZ4   = {bZ2, bZ2, bZ2, bZ2};
    const f32x4 bN4   = {bN2, bN2, bN2, bN2};
    const f32x4 zero4 = {0.f, 0.f, 0.f, 0.f};

    // ---- W_hh B-fragments (scaled), fp16 RNE ----
    f16x8 Bf[3][2];
    #pragma unroll
    for (int g = 0; g < 3; ++g) {
        const float sg = (g == 2) ? LOG2E2 : -LOG2E;
        #pragma unroll
        for (int c = 0; c < 2; ++c) {
            const float* p = Whh + ((g * 64 + q) * 64 + c * 32 + quad * 8);
            #pragma unroll
            for (int j = 0; j < 8; ++j)
                Bf[g][c][j] = (_Float16)(p[j] * sg);
        }
    }

    // persistent h-1 (fp32): lane handles batches b = quad*2 + {0,1}
    f32x2 hm1 = {-1.f, -1.f};

    // ---- swizzled LDS addressing (zero-conflict, proven R9) ----
    const int kg   = q >> 3;
    const int sxor = (kg & 1) * 4;
    int waddr[2];
    #pragma unroll
    for (int p = 0; p < 2; ++p)
        waddr[p] = (kg * 16 + ((p * 4 + quad) ^ sxor)) * 8 + (q & 7);

    const int permx = ((n16 & 3) * 4 + (n16 >> 2)) ^ ((quad & 1) * 4);
    const int rslot = quad * 16 + permx;

    const s16x8* hbv = (const s16x8*)hbuf;   // 256 slots of 8 shorts
    const float* xrow0 = xs + (quad * 2) * XSTR;
    const float* xrow1 = xrow0 + XSTR;

    // ---- anti-phase stagger for the co-resident partner wg (b, b+256) ----
    if ((blockIdx.x >> 8) & 1) __builtin_amdgcn_s_sleep(6);  // ~384 cyc, once

    auto step = [&](int cur, f32x2 xr_, f32x2 xz_, f32x2 xn_) {
        __syncthreads();
        __builtin_amdgcn_s_setprio(1);

        s16x8 A0 = hbv[cur * 128 +  0 + rslot];
        s16x8 A1 = hbv[cur * 128 + 64 + rslot];

        // R and N split (parallel MFMA pairs), Z chained (consumed last)
        f32x4 aRa = MFMA_F16(A0, Bf[0][0], bR4);
        f32x4 aRb = MFMA_F16(A1, Bf[0][1], zero4);
        f32x4 aNa = MFMA_F16(A0, Bf[2][0], bN4);
        f32x4 aNb = MFMA_F16(A1, Bf[2][1], zero4);
        f32x4 aZ  = MFMA_F16(A0, Bf[1][0], bZ4);
        aZ        = MFMA_F16(A1, Bf[1][1], aZ);

        f32x2 aR = {aRa[0] + aRb[0], aRa[1] + aRb[1]};
        f32x2 ar = xr_ + aR;
        f32x2 Er = {__builtin_amdgcn_exp2f(ar[0]), __builtin_amdgcn_exp2f(ar[1])};
        f32x2 DR = Er + 1.0f;
        f32x2 r  = {__builtin_amdgcn_rcpf(DR[0]), __builtin_amdgcn_rcpf(DR[1])};
        f32x2 aN = {aNa[0] + aNb[0], aNa[1] + aNb[1]};   // overlaps exp2/rcp
        f32x2 an = r * aN + xn_;
        f32x2 En = {__builtin_amdgcn_exp2f(an[0]), __builtin_amdgcn_exp2f(an[1])};
        f32x2 DN = En + 1.0f;

        __builtin_amdgcn_s_setprio(0);

        f32x2 az = xz_ + f32x2{aZ[0], aZ[1]};
        f32x2 Ez = {__builtin_amdgcn_exp2f(az[0]), __builtin_amdgcn_exp2f(az[1])};
        f32x2 DZ = Ez + 1.0f;
        f32x2 P  = DZ * DN;
        f32x2 iq = {__builtin_amdgcn_rcpf(P[0]), __builtin_amdgcn_rcpf(P[1])};
        f32x2 z  = iq * DN;                  // = 1/DZ = sigmoid(pre_z)
        f32x2 rn = iq * DZ;                  // = 1/DN
        f32x2 n  = rn * -2.0f + 1.0f;        // tanh
        f32x2 s  = rn *  2.0f + hm1;         // h_prev - n
        f32x2 hn = z * s + n;                // (1-z)n + z h

        hm1 = hn - 1.0f;

        h16x2 hpk = __builtin_amdgcn_cvt_pkrtz(hn[0], hn[1]);
        unsigned upk = __builtin_bit_cast(unsigned, hpk);
        short* wh = (short*)hbuf + (cur ^ 1) * 1024;
        wh[waddr[0]] = (short)(upk & 0xffffu);
        wh[waddr[1]] = (short)(upk >> 16);
    };

    f32x4 xa = *(const f32x4*)(xrow0);
    f32x4 xb = *(const f32x4*)(xrow1);
    for (int t = 0; t < TT; t += 4) {
        // precompute gate-x terms for the 4 steps (off the recurrence chain)
        f32x2 xv0 = {xa[0], xb[0]}, xv1 = {xa[1], xb[1]};
        f32x2 xv2 = {xa[2], xb[2]}, xv3 = {xa[3], xb[3]};
        f32x2 xr0 = xv0 * wr2, xz0 = xv0 * wz2, xn0 = xv0 * wn2 + bihn2;
        f32x2 xr1 = xv1 * wr2, xz1 = xv1 * wz2, xn1 = xv1 * wn2 + bihn2;
        f32x2 xr2 = xv2 * wr2, xz2 = xv2 * wz2, xn2 = xv2 * wn2 + bihn2;
        f32x2 xr3 = xv3 * wr2, xz3 = xv3 * wz2, xn3 = xv3 * wn2 + bihn2;

        step(0, xr0, xz0, xn0);

        // prefetch next x group (consumed next iteration; wrap reads row 0)
        const int tn = (t + 4 < TT) ? t + 4 : 0;
        f32x4 xan = *(const f32x4*)(xrow0 + tn);
        f32x4 xbn = *(const f32x4*)(xrow1 + tn);

        step(1, xr1, xz1, xn1);
        step(0, xr2, xz2, xn2);
        step(1, xr3, xz3, xn3);

        xa = xan; xb = xbn;
    }

    // ---- epilogue: out[b] = sum_q h[b][q]*Wout[q] + bout ----
    float p0 = (hm1[0] + 1.0f) * wo;
    float p1 = (hm1[1] + 1.0f) * wo;
    #pragma unroll
    for (int mask = 1; mask <= 8; mask <<= 1) {
        p0 += __shfl_xor(p0, mask, 64);
        p1 += __shfl_xor(p1, mask, 64);
    }
    if (n16 == 0) {
        outp[w][quad * 2]     = p0;
        outp[w][quad * 2 + 1] = p1;
    }
    __syncthreads();
    if (tid < BT) {
        out[b0 + tid] = outp[0][tid] + outp[1][tid] + outp[2][tid] + outp[3][tid] + bout[0];
    }
}

extern "C" void kernel_launch(void* const* d_in, const int* in_sizes, int n_in,
                              void* d_out, int out_size, void* d_ws, size_t ws_size,
                              hipStream_t stream) {
    (void)in_sizes; (void)n_in; (void)d_ws; (void)ws_size; (void)out_size;
    const float* x    = (const float*)d_in[0];
    const float* Wih  = (const float*)d_in[1];
    const float* Whh  = (const float*)d_in[2];
    const float* bih  = (const float*)d_in[3];
    const float* bhh  = (const float*)d_in[4];
    const float* Wout = (const float*)d_in[5];
    const float* bout = (const float*)d_in[6];
    float* out = (float*)d_out;

    gru_scan_kernel<<<dim3(4096 / BT), dim3(256), 0, stream>>>(
        x, Wih, Whh, bih, bhh, Wout, bout, out);
}

// Round 10
// 198.483 us; speedup vs baseline: 1.7574x; 1.1141x over previous
//
#include <hip/hip_runtime.h>
#include <stdint.h>

#define TT 512
#define BT 8    // 4096/8 = 512 wgs -> 2 wgs/CU -> 2 waves/SIMD (no dup work)
#define XSTR 516  // x row stride (floats): spreads t-columns across banks

typedef float    f32x4 __attribute__((ext_vector_type(4)));
typedef float    f32x2 __attribute__((ext_vector_type(2)));
typedef short    s16x8 __attribute__((ext_vector_type(8)));
typedef __fp16   h16x2 __attribute__((ext_vector_type(2)));
typedef _Float16 f16x8 __attribute__((ext_vector_type(8)));

#define MFMA_F16(A, B, C) \
    __builtin_amdgcn_mfma_f32_16x16x32_f16( \
        __builtin_bit_cast(f16x8, (A)), (B), (C), 0, 0, 0)

#define LOG2E  1.442695040888963f
#define LOG2E2 2.885390081777927f

// R16 = R15 minus s_setprio (single-variable ablation).
// R15 (178us) vs R9 (153us): bundle regressed; suspect setprio priority
// convoy -- with 2 barrier-synced wgs/SIMD, prio-1 head starves partner's
// prio-0 tail (incl. its h-write), delaying the partner's barrier and
// amplifying skew (consistent with VALUBusy 52->48, MfmaUtil 29->24.6).
// Retained chain surgery (issue-neutral):
//  - split-C MFMA for R,N gates (parallel pair + add)
//  - x-terms precomputed at group load (off the recurrence chain)
//  - hm1 carry: s = 2*rn + hm1 (removes hp-n dep)
//  - x group prefetched one iteration ahead
// Everything else (layout, swizzle, dbuf, 4-step unroll, sleep stagger,
// epilogue) is R9 verbatim.
__global__ __launch_bounds__(256, 2) void gru_scan_kernel(
    const float* __restrict__ x,     // (4096, 512, 1)
    const float* __restrict__ Wih,   // (192, 1)
    const float* __restrict__ Whh,   // (192, 64)
    const float* __restrict__ bih,   // (192)
    const float* __restrict__ bhh,   // (192)
    const float* __restrict__ Wout,  // (1, 64)
    const float* __restrict__ bout,  // (1)
    float* __restrict__ out)         // (4096, 1)
{
    __shared__ __align__(16) float xs[BT * XSTR];  // x batch-major [b][t], 16.5 KB
    __shared__ __align__(16) short hbuf[2][1024];  // [dbuf][slot*8+j], 4 KB
    __shared__ float outp[4][BT];

    const int tid  = threadIdx.x;
    const int w    = tid >> 6;
    const int L    = tid & 63;
    const int n16  = L & 15;
    const int quad = L >> 4;
    const int q    = w * 16 + n16;   // hidden col owned by this lane
    const int b0   = blockIdx.x * BT;

    // ---- stage x batch-major: xs[b][t] ----
    #pragma unroll
    for (int k = 0; k < 4; ++k) {
        int idx = tid + k * 256;          // 0..1023
        int row = idx >> 7;               // batch row 0..7
        int t4  = idx & 127;              // t/4
        f32x4 v = *(const f32x4*)(x + (size_t)(b0 + row) * TT + t4 * 4);
        *(f32x4*)(xs + row * XSTR + t4 * 4) = v;   // 16B-aligned (516*4%16==0)
    }
    // ---- zero both h double-buffers (4 KB = 256 f32x4) ----
    {
        f32x4* hb = (f32x4*)hbuf;
        f32x4 zv = {0.f, 0.f, 0.f, 0.f};
        hb[tid] = zv;
    }

    // ---- per-lane constants (gate scales folded) ----
    const float wr2   = -LOG2E  * Wih[q];
    const float wz2   = -LOG2E  * Wih[64 + q];
    const float wn2   =  LOG2E2 * Wih[128 + q];
    const float bR2   = -LOG2E  * (bih[q]      + bhh[q]);
    const float bZ2   = -LOG2E  * (bih[64 + q] + bhh[64 + q]);
    const float bN2   =  LOG2E2 * bhh[128 + q];
    const float bihn2 =  LOG2E2 * bih[128 + q];
    const float wo    = Wout[q];

    const f32x4 bR4   = {bR2, bR2, bR2, bR2};
    const f32x4 bZ4   = {bZ2, bZ2, bZ2, bZ2};
    const f32x4 bN4   = {bN2, bN2, bN2, bN2};
    const f32x4 zero4 = {0.f, 0.f, 0.f, 0.f};

    // ---- W_hh B-fragments (scaled), fp16 RNE ----
    f16x8 Bf[3][2];
    #pragma unroll
    for (int g = 0; g < 3; ++g) {
        const float sg = (g == 2) ? LOG2E2 : -LOG2E;
        #pragma unroll
        for (int c = 0; c < 2; ++c) {
            const float* p = Whh + ((g * 64 + q) * 64 + c * 32 + quad * 8);
            #pragma unroll
            for (int j = 0; j < 8; ++j)
                Bf[g][c][j] = (_Float16)(p[j] * sg);
        }
    }

    // persistent h-1 (fp32): lane handles batches b = quad*2 + {0,1}
    f32x2 hm1 = {-1.f, -1.f};

    // ---- swizzled LDS addressing (zero-conflict, proven R9) ----
    const int kg   = q >> 3;
    const int sxor = (kg & 1) * 4;
    int waddr[2];
    #pragma unroll
    for (int p = 0; p < 2; ++p)
        waddr[p] = (kg * 16 + ((p * 4 + quad) ^ sxor)) * 8 + (q & 7);

    const int permx = ((n16 & 3) * 4 + (n16 >> 2)) ^ ((quad & 1) * 4);
    const int rslot = quad * 16 + permx;

    const s16x8* hbv = (const s16x8*)hbuf;   // 256 slots of 8 shorts
    const float* xrow0 = xs + (quad * 2) * XSTR;
    const float* xrow1 = xrow0 + XSTR;

    // ---- anti-phase stagger for the co-resident partner wg (b, b+256) ----
    if ((blockIdx.x >> 8) & 1) __builtin_amdgcn_s_sleep(6);  // ~384 cyc, once

    auto step = [&](int cur, f32x2 xr_, f32x2 xz_, f32x2 xn_) {
        __syncthreads();

        s16x8 A0 = hbv[cur * 128 +  0 + rslot];
        s16x8 A1 = hbv[cur * 128 + 64 + rslot];

        // R and N split (parallel MFMA pairs), Z chained (consumed last)
        f32x4 aRa = MFMA_F16(A0, Bf[0][0], bR4);
        f32x4 aRb = MFMA_F16(A1, Bf[0][1], zero4);
        f32x4 aNa = MFMA_F16(A0, Bf[2][0], bN4);
        f32x4 aNb = MFMA_F16(A1, Bf[2][1], zero4);
        f32x4 aZ  = MFMA_F16(A0, Bf[1][0], bZ4);
        aZ        = MFMA_F16(A1, Bf[1][1], aZ);

        f32x2 aR = {aRa[0] + aRb[0], aRa[1] + aRb[1]};
        f32x2 ar = xr_ + aR;
        f32x2 Er = {__builtin_amdgcn_exp2f(ar[0]), __builtin_amdgcn_exp2f(ar[1])};
        f32x2 DR = Er + 1.0f;
        f32x2 r  = {__builtin_amdgcn_rcpf(DR[0]), __builtin_amdgcn_rcpf(DR[1])};
        f32x2 aN = {aNa[0] + aNb[0], aNa[1] + aNb[1]};   // overlaps exp2/rcp
        f32x2 an = r * aN + xn_;
        f32x2 En = {__builtin_amdgcn_exp2f(an[0]), __builtin_amdgcn_exp2f(an[1])};
        f32x2 DN = En + 1.0f;

        f32x2 az = xz_ + f32x2{aZ[0], aZ[1]};
        f32x2 Ez = {__builtin_amdgcn_exp2f(az[0]), __builtin_amdgcn_exp2f(az[1])};
        f32x2 DZ = Ez + 1.0f;
        f32x2 P  = DZ * DN;
        f32x2 iq = {__builtin_amdgcn_rcpf(P[0]), __builtin_amdgcn_rcpf(P[1])};
        f32x2 z  = iq * DN;                  // = 1/DZ = sigmoid(pre_z)
        f32x2 rn = iq * DZ;                  // = 1/DN
        f32x2 n  = rn * -2.0f + 1.0f;        // tanh
        f32x2 s  = rn *  2.0f + hm1;         // h_prev - n
        f32x2 hn = z * s + n;                // (1-z)n + z h

        hm1 = hn - 1.0f;

        h16x2 hpk = __builtin_amdgcn_cvt_pkrtz(hn[0], hn[1]);
        unsigned upk = __builtin_bit_cast(unsigned, hpk);
        short* wh = (short*)hbuf + (cur ^ 1) * 1024;
        wh[waddr[0]] = (short)(upk & 0xffffu);
        wh[waddr[1]] = (short)(upk >> 16);
    };

    f32x4 xa = *(const f32x4*)(xrow0);
    f32x4 xb = *(const f32x4*)(xrow1);
    for (int t = 0; t < TT; t += 4) {
        // precompute gate-x terms for the 4 steps (off the recurrence chain)
        f32x2 xv0 = {xa[0], xb[0]}, xv1 = {xa[1], xb[1]};
        f32x2 xv2 = {xa[2], xb[2]}, xv3 = {xa[3], xb[3]};
        f32x2 xr0 = xv0 * wr2, xz0 = xv0 * wz2, xn0 = xv0 * wn2 + bihn2;
        f32x2 xr1 = xv1 * wr2, xz1 = xv1 * wz2, xn1 = xv1 * wn2 + bihn2;
        f32x2 xr2 = xv2 * wr2, xz2 = xv2 * wz2, xn2 = xv2 * wn2 + bihn2;
        f32x2 xr3 = xv3 * wr2, xz3 = xv3 * wz2, xn3 = xv3 * wn2 + bihn2;

        step(0, xr0, xz0, xn0);

        // prefetch next x group (consumed next iteration; wrap reads row 0)
        const int tn = (t + 4 < TT) ? t + 4 : 0;
        f32x4 xan = *(const f32x4*)(xrow0 + tn);
        f32x4 xbn = *(const f32x4*)(xrow1 + tn);

        step(1, xr1, xz1, xn1);
        step(0, xr2, xz2, xn2);
        step(1, xr3, xz3, xn3);

        xa = xan; xb = xbn;
    }

    // ---- epilogue: out[b] = sum_q h[b][q]*Wout[q] + bout ----
    float p0 = (hm1[0] + 1.0f) * wo;
    float p1 = (hm1[1] + 1.0f) * wo;
    #pragma unroll
    for (int mask = 1; mask <= 8; mask <<= 1) {
        p0 += __shfl_xor(p0, mask, 64);
        p1 += __shfl_xor(p1, mask, 64);
    }
    if (n16 == 0) {
        outp[w][quad * 2]     = p0;
        outp[w][quad * 2 + 1] = p1;
    }
    __syncthreads();
    if (tid < BT) {
        out[b0 + tid] = outp[0][tid] + outp[1][tid] + outp[2][tid] + outp[3][tid] + bout[0];
    }
}

extern "C" void kernel_launch(void* const* d_in, const int* in_sizes, int n_in,
                              void* d_out, int out_size, void* d_ws, size_t ws_size,
                              hipStream_t stream) {
    (void)in_sizes; (void)n_in; (void)d_ws; (void)ws_size; (void)out_size;
    const float* x    = (const float*)d_in[0];
    const float* Wih  = (const float*)d_in[1];
    const float* Whh  = (const float*)d_in[2];
    const float* bih  = (const float*)d_in[3];
    const float* bhh  = (const float*)d_in[4];
    const float* Wout = (const float*)d_in[5];
    const float* bout = (const float*)d_in[6];
    float* out = (float*)d_out;

    gru_scan_kernel<<<dim3(4096 / BT), dim3(256), 0, stream>>>(
        x, Wih, Whh, bih, bhh, Wout, bout, out);
}